// Round 5
// baseline (115.916 us; speedup 1.0000x reference)
//
#include <hip/hip_runtime.h>

// FeatureFusionModule: fused = concat(shared, special, axis=1) [65536, 2048]
//   fusion_features = fused.reshape(16384, 4, 2048).sum(axis=1)   -> [16384, 2048] f32
//   fusion_pids     = pids[::4]                                   -> [16384] (written as float)
// d_out layout: 16384*2048 floats of features, then 16384 floats of pids.
//
// R1: 134.5 us cached.  R2: 127.3 us NT stores.  R3: 119.0 us all-NT.
// R4: 114.0 us, 4 out/thread, 16 loads in flight (5.89 TB/s = 94% of copy ceiling).
// R5: 8 out/thread, 32 NT loads issued back-to-back (512 B in flight/thread).
//     Block tile = 2048 consecutive f4 (4 output rows); thread t handles
//     j = blockIdx*2048 + t + 256*k, k=0..7. Exact grid, no tail.

using f4 = __attribute__((ext_vector_type(4))) float;

__global__ __launch_bounds__(256) void feature_fusion_kernel(
    const f4* __restrict__ shf,      // [bs][256] float4
    const f4* __restrict__ spf,      // [bs][256] float4
    const int* __restrict__ pids,    // [bs]
    f4* __restrict__ out,            // [chunk][512] float4
    float* __restrict__ out_pids)    // [chunk]
{
    const int j0 = blockIdx.x * 2048 + threadIdx.x;  // block tile: 2048 f4

    f4 v[8][4];                      // [k-group][input row]
#pragma unroll
    for (int k = 0; k < 8; ++k) {
        const int j = j0 + (k << 8);
        const int i = j >> 9;          // output row
        const int c = j & 511;         // f4 column in output row
        const f4* __restrict__ src = (c < 256) ? shf : spf;  // wave-uniform
        const size_t base = (size_t)i * 1024 + (size_t)(c & 255);
        v[k][0] = __builtin_nontemporal_load(&src[base]);
        v[k][1] = __builtin_nontemporal_load(&src[base + 256]);
        v[k][2] = __builtin_nontemporal_load(&src[base + 512]);
        v[k][3] = __builtin_nontemporal_load(&src[base + 768]);
    }
#pragma unroll
    for (int k = 0; k < 8; ++k) {
        const int j = j0 + (k << 8);
        f4 r = (v[k][0] + v[k][1]) + (v[k][2] + v[k][3]);
        __builtin_nontemporal_store(r, &out[j]);
        if ((j & 511) == 0) {
            const int i = j >> 9;
            float p = (float)pids[(size_t)i * 4];
            __builtin_nontemporal_store(p, &out_pids[i]);
        }
    }
}

extern "C" void kernel_launch(void* const* d_in, const int* in_sizes, int n_in,
                              void* d_out, int out_size, void* d_ws, size_t ws_size,
                              hipStream_t stream) {
    const f4*  shf  = (const f4*)d_in[0];
    const f4*  spf  = (const f4*)d_in[1];
    const int* pids = (const int*)d_in[2];

    const int bs    = in_sizes[2];          // 65536
    const int d     = in_sizes[0] / bs;     // 1024
    const int chunk = bs / 4;               // 16384
    const int total_f4 = chunk * (2 * d / 4);  // 8388608

    float* out      = (float*)d_out;
    float* out_pids = out + (size_t)chunk * (size_t)(2 * d);  // after features

    const int block = 256;
    const int grid  = total_f4 / 2048;      // 4096 blocks, exact (no tail)
    feature_fusion_kernel<<<grid, block, 0, stream>>>(shf, spf, pids,
                                                      (f4*)out, out_pids);
}

// Round 6
// 114.401 us; speedup vs baseline: 1.0132x; 1.0132x over previous
//
#include <hip/hip_runtime.h>

// FeatureFusionModule: fused = concat(shared, special, axis=1) [65536, 2048]
//   fusion_features = fused.reshape(16384, 4, 2048).sum(axis=1)   -> [16384, 2048] f32
//   fusion_pids     = pids[::4]                                   -> [16384] (written as float)
// d_out layout: 16384*2048 floats of features, then 16384 floats of pids.
//
// R1: 134.5 us cached.  R2: 127.3 us NT stores.  R3: 119.0 us all-NT.
// R4: 114.0 us, 4 out/thread, 16 NT loads in flight (5.89 TB/s = 94% of copy ceiling). BEST.
// R5: 8 out/thread regressed (115.9 us) -> request-depth lever exhausted; revert to R4.
// Roofline: 671 MB compulsory traffic / 6.29 TB/s copy ceiling = 107 us floor; we
// sit 6% above it (DRAM r/w turnaround on the 4:1 mix). Declaring done.

using f4 = __attribute__((ext_vector_type(4))) float;

__global__ __launch_bounds__(256) void feature_fusion_kernel(
    const f4* __restrict__ shf,      // [bs][256] float4
    const f4* __restrict__ spf,      // [bs][256] float4
    const int* __restrict__ pids,    // [bs]
    f4* __restrict__ out,            // [chunk][512] float4
    float* __restrict__ out_pids)    // [chunk]
{
    const int j0 = blockIdx.x * 1024 + threadIdx.x;  // block tile: 1024 f4

    f4 v[4][4];                      // [k-group][input row]
#pragma unroll
    for (int k = 0; k < 4; ++k) {
        const int j = j0 + (k << 8);
        const int i = j >> 9;          // output row
        const int c = j & 511;         // f4 column in output row
        const f4* __restrict__ src = (c < 256) ? shf : spf;  // wave-uniform
        const size_t base = (size_t)i * 1024 + (size_t)(c & 255);
        v[k][0] = __builtin_nontemporal_load(&src[base]);
        v[k][1] = __builtin_nontemporal_load(&src[base + 256]);
        v[k][2] = __builtin_nontemporal_load(&src[base + 512]);
        v[k][3] = __builtin_nontemporal_load(&src[base + 768]);
    }
#pragma unroll
    for (int k = 0; k < 4; ++k) {
        const int j = j0 + (k << 8);
        f4 r = (v[k][0] + v[k][1]) + (v[k][2] + v[k][3]);
        __builtin_nontemporal_store(r, &out[j]);
        if ((j & 511) == 0) {
            const int i = j >> 9;
            float p = (float)pids[(size_t)i * 4];
            __builtin_nontemporal_store(p, &out_pids[i]);
        }
    }
}

extern "C" void kernel_launch(void* const* d_in, const int* in_sizes, int n_in,
                              void* d_out, int out_size, void* d_ws, size_t ws_size,
                              hipStream_t stream) {
    const f4*  shf  = (const f4*)d_in[0];
    const f4*  spf  = (const f4*)d_in[1];
    const int* pids = (const int*)d_in[2];

    const int bs    = in_sizes[2];          // 65536
    const int d     = in_sizes[0] / bs;     // 1024
    const int chunk = bs / 4;               // 16384
    const int total_f4 = chunk * (2 * d / 4);  // 8388608

    float* out      = (float*)d_out;
    float* out_pids = out + (size_t)chunk * (size_t)(2 * d);  // after features

    const int block = 256;
    const int grid  = total_f4 / 1024;      // 8192 blocks, exact (no tail)
    feature_fusion_kernel<<<grid, block, 0, stream>>>(shf, spf, pids,
                                                      (f4*)out, out_pids);
}